// Round 12
// baseline (162.599 us; speedup 1.0000x reference)
//
#include <hip/hip_runtime.h>
#include <hip/hip_bf16.h>

#define B_    128
#define N_    4096
#define DIM_  16
#define HID_  128
#define NT_   4             // grid.x tiles -> 512 blocks, 2 resident/CU
#define ROWS_ (N_ / NT_)    // 1024 adj rows per block

typedef __bf16 bf16x8 __attribute__((ext_vector_type(8)));
typedef float floatx16 __attribute__((ext_vector_type(16)));
typedef unsigned int u32;

__device__ inline bf16x8 load_cvt8(const float* __restrict__ p) {
  const float4 u = *(const float4*)p;
  const float4 v = *(const float4*)(p + 4);
  bf16x8 r;
  r[0] = (__bf16)u.x; r[1] = (__bf16)u.y; r[2] = (__bf16)u.z; r[3] = (__bf16)u.w;
  r[4] = (__bf16)v.x; r[5] = (__bf16)v.y; r[6] = (__bf16)v.z; r[7] = (__bf16)v.w;
  return r;
}

// R12 = R11 (zero-shuffle pi-permuted repack, register-resident W2 B-frags,
// ballot compaction, spare-K bias MFMA, (256,2) no-spill envelope) + tail
// fused via last-block-per-batch: per-batch device-scope counter in ws;
// the 4th finishing block of each batch runs the small fp32 tail inline.
// Removes the second dispatch + its launch/drain gap.
__global__ __launch_bounds__(256, 2) void edge_kernel(
    const float* __restrict__ x, const float* __restrict__ adj,
    const float* __restrict__ W1, const float* __restrict__ b1,
    const float* __restrict__ W2, const float* __restrict__ b2,
    const float* __restrict__ W3, const float* __restrict__ b3,
    const float* __restrict__ W4, const float* __restrict__ b4,
    const float* __restrict__ W5, const float* __restrict__ b5,
    const int* __restrict__ ip, float* __restrict__ part,
    int* __restrict__ cnt_g, float* __restrict__ out)
{
  // sW2: col c = 128 contiguous bf16 (16 granules of 8), granule slot gg^(c&15),
  // rows bit2<->bit3-permuted: granule gg element j holds
  // W2[16*(gg>>1) + 8*(j>>2) + 4*(gg&1) + (j&3)][c].
  __shared__ __align__(16) __bf16 sW2[HID_ * HID_];
  __shared__ __align__(16) float sW1s[DIM_][HID_];   // W1 starter rows, coalesced staged
  __shared__ int   sIdx[ROWS_ + 192];
  __shared__ float sAcc[HID_];
  __shared__ float sB1[HID_];
  __shared__ float sEnder[DIM_];
  __shared__ float sT0[HID_], sT1[HID_];             // fused-tail scratch
  __shared__ int   sCnt;
  __shared__ int   sLast;

  const int t  = threadIdx.x;
  const int b  = blockIdx.y;
  const int n0 = blockIdx.x * ROWS_;
  const int ii = __ldg(ip);

  const int wave = t >> 6, lane = t & 63;
  const int half = lane >> 5, l31 = lane & 31;
  const int rg = wave >> 1;           // row-group: chunks rg*32, step 64
  const int ch = wave & 1;            // col-half: cols ch*64 .. ch*64+63

  if (t == 0) sCnt = 0;
  if (t < HID_) sAcc[t] = 0.f;
  if (t < DIM_) sEnder[t] = x[((size_t)b * N_ + ii) * DIM_ + t];
  __syncthreads();

  // ---- ballot-based compaction: 1 LDS atomic per wave-iter ----
  #pragma unroll
  for (int r = t; r < ROWS_; r += 256) {
    const bool act = adj[n0 + r] != 0.f;
    const unsigned long long m = __ballot(act);
    int base = 0;
    if (lane == 0) base = atomicAdd(&sCnt, __popcll(m));
    base = __shfl(base, 0);
    if (act) {
      const int pre = __builtin_amdgcn_mbcnt_hi((u32)(m >> 32),
                      __builtin_amdgcn_mbcnt_lo((u32)m, 0));
      sIdx[base + pre] = n0 + r;
    }
  }

  // ---- W1 starter rows -> LDS, fully coalesced ----
  #pragma unroll
  for (int e = t; e < DIM_ * HID_; e += 256) sW1s[e >> 7][e & 127] = W1[e];

  // ---- stage W2^T into LDS, bf16, XOR-swizzled granules, pi-permuted rows ----
  #pragma unroll
  for (int e = 0; e < 8; ++e) {
    const int G = t * 8 + e;            // granule id: c = G>>4, gg = G&15
    const int c = G >> 4, gg = G & 15;
    bf16x8 v;
    #pragma unroll
    for (int j = 0; j < 8; ++j) {
      const int row = ((gg >> 1) << 4) + ((j >> 2) << 3) + ((gg & 1) << 2) + (j & 3);
      v[j] = (__bf16)W2[row * HID_ + c];
    }
    *(bf16x8*)&sW2[(c << 7) + ((gg ^ (c & 15)) << 3)] = v;
  }

  // ---- cooperative ender-fold: sB1[f] = b1[f] + ender . W1[16:32, f] ----
  if (t < HID_) {
    float s = b1[t];
    #pragma unroll
    for (int k = 0; k < DIM_; ++k) s += sEnder[k] * W1[(DIM_ + k) * HID_ + t];
    sB1[t] = s;
  }

  const float bv0 = b2[ch * 64 + l31], bv1 = b2[ch * 64 + 32 + l31];

  __syncthreads();                       // sIdx/sCnt/sW2/sW1s/sB1 ready
  const int cnt = sCnt;
  const int nch64 = (cnt + 63) >> 6;
  const int end = nch64 * 64;
  for (int p = cnt + t; p < end + 128; p += 256) sIdx[p] = n0;  // pad + prefetch slack

  // W1^T A-frags from LDS (m=feat=l31+32ft, k=half*8+j)
  bf16x8 w1f[4];
  #pragma unroll
  for (int ft = 0; ft < 4; ++ft) {
    bf16x8 v;
    #pragma unroll
    for (int j = 0; j < 8; ++j) v[j] = (__bf16)sW1s[half * 8 + j][ft * 32 + l31];
    w1f[ft] = v;
  }

  // ---- W2 B-frags for this wave's col-half: read ONCE from swizzled LDS ----
  bf16x8 w2r[16];                        // [s] = col-tile0, [8+s] = col-tile1
  {
    const int c0 = ch * 64 + l31;
    const __bf16* base0 = &sW2[(c0 << 7)];
    const __bf16* base1 = &sW2[((c0 + 32) << 7)];
    #pragma unroll
    for (int s = 0; s < 8; ++s) {
      const int gp = ((s << 1) + half) ^ (c0 & 15);
      w2r[s]     = *(const bf16x8*)(base0 + (gp << 3));
      w2r[8 + s] = *(const bf16x8*)(base1 + (gp << 3));
    }
  }

  // bias delivered via spare-K MFMA (k=0: bf16 hi, k=1: bf16 residual)
  bf16x8 a2f[4], onef;
  #pragma unroll
  for (int j = 0; j < 8; ++j) onef[j] = (__bf16)0.f;
  if (half == 0) { onef[0] = (__bf16)1.f; onef[1] = (__bf16)1.f; }
  #pragma unroll
  for (int ft = 0; ft < 4; ++ft) {
    bf16x8 v;
    #pragma unroll
    for (int j = 0; j < 8; ++j) v[j] = (__bf16)0.f;
    if (half == 0) {
      const float s = sB1[ft * 32 + l31];
      const __bf16 hi = (__bf16)s;
      v[0] = hi;
      v[1] = (__bf16)(s - (float)hi);
    }
    a2f[ft] = v;
  }
  __syncthreads();                       // pad visible

  float sum0 = 0.f, sum1 = 0.f;
  floatx16 zf;
  #pragma unroll
  for (int r = 0; r < 16; ++r) zf[r] = 0.f;

  // prefetch first gather (pad guarantees sIdx valid)
  int cb = rg * 32;
  bf16x8 xf;
  {
    const int row = sIdx[cb + l31];
    xf = load_cvt8(&x[((size_t)b * N_ + row) * DIM_ + half * 8]);
  }

  for (; cb < end; cb += 64) {
    const int nrow = sIdx[cb + 64 + l31];            // next iter (pad-safe)

    // ---- stage A: h1^T tiles; pi-permutation makes the repack register-local ----
    bf16x8 af[8];                        // stage-B A-frags, k = s*16 + half*8 + j
    #pragma unroll
    for (int ft = 0; ft < 4; ++ft) {
      floatx16 hc = __builtin_amdgcn_mfma_f32_32x32x16_bf16(w1f[ft], xf, zf, 0, 0, 0);
      hc = __builtin_amdgcn_mfma_f32_32x32x16_bf16(a2f[ft], onef, hc, 0, 0, 0);
      bf16x8 a0, a1;
      #pragma unroll
      for (int j = 0; j < 8; ++j) {
        a0[j] = (__bf16)fmaxf(hc[j],     0.f);
        a1[j] = (__bf16)fmaxf(hc[8 + j], 0.f);
      }
      af[2 * ft]     = a0;
      af[2 * ft + 1] = a1;
    }

    // prefetch next x gather; its waitcnt lands after stage B
    const bf16x8 nxf = load_cvt8(&x[((size_t)b * N_ + nrow) * DIM_ + half * 8]);

    // ---- stage B: 32 rows x 64 cols, K=128; B-frags from REGISTERS ----
    floatx16 c0 = zf, c1 = zf;
    #pragma unroll
    for (int s = 0; s < 8; ++s) {
      c0 = __builtin_amdgcn_mfma_f32_32x32x16_bf16(af[s], w2r[s],     c0, 0, 0, 0);
      c1 = __builtin_amdgcn_mfma_f32_32x32x16_bf16(af[s], w2r[8 + s], c1, 0, 0, 0);
    }

    // ---- epilogue: bias + relu + row-sum (row m=(r&3)+8*(r>>2)+4*half) ----
    if (cb + 32 <= cnt) {
      #pragma unroll
      for (int r = 0; r < 16; ++r) {
        sum0 += fmaxf(c0[r] + bv0, 0.f);
        sum1 += fmaxf(c1[r] + bv1, 0.f);
      }
    } else {
      #pragma unroll
      for (int r = 0; r < 16; ++r) {
        const int q = cb + (r & 3) + ((r >> 2) << 3) + (half << 2);
        if (q < cnt) {
          sum0 += fmaxf(c0[r] + bv0, 0.f);
          sum1 += fmaxf(c1[r] + bv1, 0.f);
        }
      }
    }
    xf = nxf;
  }

  // fold halves; two waves share each col-half -> LDS atomics
  sum0 += __shfl_xor(sum0, 32);
  sum1 += __shfl_xor(sum1, 32);
  if (half == 0) {
    atomicAdd(&sAcc[ch * 64 + l31],      sum0);
    atomicAdd(&sAcc[ch * 64 + 32 + l31], sum1);
  }
  __syncthreads();
  if (t < HID_) part[((size_t)b * NT_ + blockIdx.x) * HID_ + t] = sAcc[t];

  // ---- last-block-per-batch: run the fp32 tail inline ----
  if (t == 0) {
    __threadfence();                               // release part writes (device scope)
    sLast = (atomicAdd(&cnt_g[b], 1) == NT_ - 1);  // device-scope atomic
  }
  __syncthreads();
  if (!sLast) return;
  __threadfence();                                 // acquire other blocks' part writes

  if (t < HID_) {
    float a = 0.f;
    #pragma unroll
    for (int p = 0; p < NT_; ++p) a += part[((size_t)b * NT_ + p) * HID_ + t];
    sT0[t] = a;
  }
  __syncthreads();
  if (t < HID_) {
    float v = b3[t];
    #pragma unroll 16
    for (int k = 0; k < HID_; ++k) v += sT0[k] * W3[k * HID_ + t];
    sT1[t] = fmaxf(v, 0.f);
  }
  __syncthreads();
  if (t < HID_) {
    float w = b4[t];
    #pragma unroll 16
    for (int k = 0; k < HID_; ++k) w += sT1[k] * W4[k * HID_ + t];
    sT0[t] = fmaxf(w, 0.f);                        // sT0 now = h4
  }
  __syncthreads();
  if (t < DIM_) {
    float o = b5[t];
    #pragma unroll
    for (int k = 0; k < DIM_; ++k) o += sEnder[k] * W5[k * DIM_ + t];
    #pragma unroll 16
    for (int k = 0; k < HID_; ++k) o += sT0[k] * W5[(DIM_ + k) * DIM_ + t];
    out[b * DIM_ + t] = o;
  }
}

extern "C" void kernel_launch(void* const* d_in, const int* in_sizes, int n_in,
                              void* d_out, int out_size, void* d_ws, size_t ws_size,
                              hipStream_t stream) {
  const float* x   = (const float*)d_in[0];
  const float* adj = (const float*)d_in[1];
  const float* W1  = (const float*)d_in[2];   // W_n2e [32,128]
  const float* b1  = (const float*)d_in[3];
  const float* W2  = (const float*)d_in[4];   // W_e2e [128,128]
  const float* b2  = (const float*)d_in[5];
  const float* W3  = (const float*)d_in[6];   // W_e2n
  const float* b3  = (const float*)d_in[7];
  const float* W4  = (const float*)d_in[8];   // W_n2n
  const float* b4  = (const float*)d_in[9];
  const float* W5  = (const float*)d_in[10];  // W_out [144,16]
  const float* b5  = (const float*)d_in[11];
  const int*   ip  = (const int*)d_in[12];
  float* out  = (float*)d_out;
  float* part = (float*)d_ws;                 // [B, NT_, HID] fp32 partials
  int*   cntg = (int*)((char*)d_ws + (size_t)B_ * NT_ * HID_ * sizeof(float));

  hipMemsetAsync(cntg, 0, B_ * sizeof(int), stream);   // counters (ws is 0xAA-poisoned)
  edge_kernel<<<dim3(NT_, B_), 256, 0, stream>>>(x, adj, W1, b1, W2, b2,
                                                 W3, b3, W4, b4, W5, b5,
                                                 ip, part, cntg, out);
}

// Round 13
// 128.516 us; speedup vs baseline: 1.2652x; 1.2652x over previous
//
#include <hip/hip_runtime.h>
#include <hip/hip_bf16.h>

#define B_    128
#define N_    4096
#define DIM_  16
#define HID_  128
#define NT_   4             // grid.x tiles -> 512 blocks, 2 resident/CU
#define ROWS_ (N_ / NT_)    // 1024 adj rows per block

typedef __bf16 bf16x8 __attribute__((ext_vector_type(8)));
typedef float floatx16 __attribute__((ext_vector_type(16)));
typedef unsigned int u32;

__device__ inline bf16x8 load_cvt8(const float* __restrict__ p) {
  const float4 u = *(const float4*)p;
  const float4 v = *(const float4*)(p + 4);
  bf16x8 r;
  r[0] = (__bf16)u.x; r[1] = (__bf16)u.y; r[2] = (__bf16)u.z; r[3] = (__bf16)u.w;
  r[4] = (__bf16)v.x; r[5] = (__bf16)v.y; r[6] = (__bf16)v.z; r[7] = (__bf16)v.w;
  return r;
}

// R13 = R11's edge (zero-shuffle pi-permuted repack, register-resident W2
// B-frags, ballot compaction, spare-K bias MFMA, (256,2) no-spill envelope)
// + FENCE-FREE fused tail: part written via agent-scope relaxed atomic
// stores, per-batch counter via agent-scope acq_rel fetch_add (release
// sequence provides visibility -- NO __threadfence, NO L2 writeback, which
// was R12's 54us regression). Last block per batch runs the fp32 tail inline
// (scratch aliases dead sW1s). Saves the ~12us tail dispatch + graph gap
// measured in R12's non-edge floor (79.6 vs ~92).
__global__ __launch_bounds__(256, 2) void edge_kernel(
    const float* __restrict__ x, const float* __restrict__ adj,
    const float* __restrict__ W1, const float* __restrict__ b1,
    const float* __restrict__ W2, const float* __restrict__ b2,
    const float* __restrict__ W3, const float* __restrict__ b3,
    const float* __restrict__ W4, const float* __restrict__ b4,
    const float* __restrict__ W5, const float* __restrict__ b5,
    const int* __restrict__ ip, float* __restrict__ part,
    int* __restrict__ cnt_g, float* __restrict__ out)
{
  // sW2: col c = 128 contiguous bf16 (16 granules of 8), granule slot gg^(c&15),
  // rows bit2<->bit3-permuted: granule gg element j holds
  // W2[16*(gg>>1) + 8*(j>>2) + 4*(gg&1) + (j&3)][c].
  __shared__ __align__(16) __bf16 sW2[HID_ * HID_];
  __shared__ __align__(16) float sW1s[DIM_][HID_];   // W1 staging; reused as tail scratch
  __shared__ int   sIdx[ROWS_ + 192];
  __shared__ float sAcc[HID_];
  __shared__ float sB1[HID_];
  __shared__ float sEnder[DIM_];
  __shared__ int   sCnt;
  __shared__ int   sLast;

  const int t  = threadIdx.x;
  const int b  = blockIdx.y;
  const int n0 = blockIdx.x * ROWS_;
  const int ii = __ldg(ip);

  const int wave = t >> 6, lane = t & 63;
  const int half = lane >> 5, l31 = lane & 31;
  const int rg = wave >> 1;           // row-group: chunks rg*32, step 64
  const int ch = wave & 1;            // col-half: cols ch*64 .. ch*64+63

  if (t == 0) sCnt = 0;
  if (t < HID_) sAcc[t] = 0.f;
  if (t < DIM_) sEnder[t] = x[((size_t)b * N_ + ii) * DIM_ + t];
  __syncthreads();

  // ---- ballot-based compaction: 1 LDS atomic per wave-iter ----
  #pragma unroll
  for (int r = t; r < ROWS_; r += 256) {
    const bool act = adj[n0 + r] != 0.f;
    const unsigned long long m = __ballot(act);
    int base = 0;
    if (lane == 0) base = atomicAdd(&sCnt, __popcll(m));
    base = __shfl(base, 0);
    if (act) {
      const int pre = __builtin_amdgcn_mbcnt_hi((u32)(m >> 32),
                      __builtin_amdgcn_mbcnt_lo((u32)m, 0));
      sIdx[base + pre] = n0 + r;
    }
  }

  // ---- W1 starter rows -> LDS, fully coalesced ----
  #pragma unroll
  for (int e = t; e < DIM_ * HID_; e += 256) sW1s[e >> 7][e & 127] = W1[e];

  // ---- stage W2^T into LDS, bf16, XOR-swizzled granules, pi-permuted rows ----
  #pragma unroll
  for (int e = 0; e < 8; ++e) {
    const int G = t * 8 + e;            // granule id: c = G>>4, gg = G&15
    const int c = G >> 4, gg = G & 15;
    bf16x8 v;
    #pragma unroll
    for (int j = 0; j < 8; ++j) {
      const int row = ((gg >> 1) << 4) + ((j >> 2) << 3) + ((gg & 1) << 2) + (j & 3);
      v[j] = (__bf16)W2[row * HID_ + c];
    }
    *(bf16x8*)&sW2[(c << 7) + ((gg ^ (c & 15)) << 3)] = v;
  }

  // ---- cooperative ender-fold: sB1[f] = b1[f] + ender . W1[16:32, f] ----
  if (t < HID_) {
    float s = b1[t];
    #pragma unroll
    for (int k = 0; k < DIM_; ++k) s += sEnder[k] * W1[(DIM_ + k) * HID_ + t];
    sB1[t] = s;
  }

  const float bv0 = b2[ch * 64 + l31], bv1 = b2[ch * 64 + 32 + l31];

  __syncthreads();                       // sIdx/sCnt/sW2/sW1s/sB1 ready
  const int cnt = sCnt;
  const int nch64 = (cnt + 63) >> 6;
  const int end = nch64 * 64;
  for (int p = cnt + t; p < end + 128; p += 256) sIdx[p] = n0;  // pad + prefetch slack

  // W1^T A-frags from LDS (m=feat=l31+32ft, k=half*8+j)
  bf16x8 w1f[4];
  #pragma unroll
  for (int ft = 0; ft < 4; ++ft) {
    bf16x8 v;
    #pragma unroll
    for (int j = 0; j < 8; ++j) v[j] = (__bf16)sW1s[half * 8 + j][ft * 32 + l31];
    w1f[ft] = v;
  }

  // ---- W2 B-frags for this wave's col-half: read ONCE from swizzled LDS ----
  bf16x8 w2r[16];                        // [s] = col-tile0, [8+s] = col-tile1
  {
    const int c0 = ch * 64 + l31;
    const __bf16* base0 = &sW2[(c0 << 7)];
    const __bf16* base1 = &sW2[((c0 + 32) << 7)];
    #pragma unroll
    for (int s = 0; s < 8; ++s) {
      const int gp = ((s << 1) + half) ^ (c0 & 15);
      w2r[s]     = *(const bf16x8*)(base0 + (gp << 3));
      w2r[8 + s] = *(const bf16x8*)(base1 + (gp << 3));
    }
  }

  // bias delivered via spare-K MFMA (k=0: bf16 hi, k=1: bf16 residual)
  bf16x8 a2f[4], onef;
  #pragma unroll
  for (int j = 0; j < 8; ++j) onef[j] = (__bf16)0.f;
  if (half == 0) { onef[0] = (__bf16)1.f; onef[1] = (__bf16)1.f; }
  #pragma unroll
  for (int ft = 0; ft < 4; ++ft) {
    bf16x8 v;
    #pragma unroll
    for (int j = 0; j < 8; ++j) v[j] = (__bf16)0.f;
    if (half == 0) {
      const float s = sB1[ft * 32 + l31];
      const __bf16 hi = (__bf16)s;
      v[0] = hi;
      v[1] = (__bf16)(s - (float)hi);
    }
    a2f[ft] = v;
  }
  __syncthreads();                       // pad visible

  float sum0 = 0.f, sum1 = 0.f;
  floatx16 zf;
  #pragma unroll
  for (int r = 0; r < 16; ++r) zf[r] = 0.f;

  // prefetch first gather (pad guarantees sIdx valid)
  int cb = rg * 32;
  bf16x8 xf;
  {
    const int row = sIdx[cb + l31];
    xf = load_cvt8(&x[((size_t)b * N_ + row) * DIM_ + half * 8]);
  }

  for (; cb < end; cb += 64) {
    const int nrow = sIdx[cb + 64 + l31];            // next iter (pad-safe)

    // ---- stage A: h1^T tiles; pi-permutation makes the repack register-local ----
    bf16x8 af[8];                        // stage-B A-frags, k = s*16 + half*8 + j
    #pragma unroll
    for (int ft = 0; ft < 4; ++ft) {
      floatx16 hc = __builtin_amdgcn_mfma_f32_32x32x16_bf16(w1f[ft], xf, zf, 0, 0, 0);
      hc = __builtin_amdgcn_mfma_f32_32x32x16_bf16(a2f[ft], onef, hc, 0, 0, 0);
      bf16x8 a0, a1;
      #pragma unroll
      for (int j = 0; j < 8; ++j) {
        a0[j] = (__bf16)fmaxf(hc[j],     0.f);
        a1[j] = (__bf16)fmaxf(hc[8 + j], 0.f);
      }
      af[2 * ft]     = a0;
      af[2 * ft + 1] = a1;
    }

    // prefetch next x gather; its waitcnt lands after stage B
    const bf16x8 nxf = load_cvt8(&x[((size_t)b * N_ + nrow) * DIM_ + half * 8]);

    // ---- stage B: 32 rows x 64 cols, K=128; B-frags from REGISTERS ----
    floatx16 c0 = zf, c1 = zf;
    #pragma unroll
    for (int s = 0; s < 8; ++s) {
      c0 = __builtin_amdgcn_mfma_f32_32x32x16_bf16(af[s], w2r[s],     c0, 0, 0, 0);
      c1 = __builtin_amdgcn_mfma_f32_32x32x16_bf16(af[s], w2r[8 + s], c1, 0, 0, 0);
    }

    // ---- epilogue: bias + relu + row-sum (row m=(r&3)+8*(r>>2)+4*half) ----
    if (cb + 32 <= cnt) {
      #pragma unroll
      for (int r = 0; r < 16; ++r) {
        sum0 += fmaxf(c0[r] + bv0, 0.f);
        sum1 += fmaxf(c1[r] + bv1, 0.f);
      }
    } else {
      #pragma unroll
      for (int r = 0; r < 16; ++r) {
        const int q = cb + (r & 3) + ((r >> 2) << 3) + (half << 2);
        if (q < cnt) {
          sum0 += fmaxf(c0[r] + bv0, 0.f);
          sum1 += fmaxf(c1[r] + bv1, 0.f);
        }
      }
    }
    xf = nxf;
  }

  // fold halves; two waves share each col-half -> LDS atomics
  sum0 += __shfl_xor(sum0, 32);
  sum1 += __shfl_xor(sum1, 32);
  if (half == 0) {
    atomicAdd(&sAcc[ch * 64 + l31],      sum0);
    atomicAdd(&sAcc[ch * 64 + 32 + l31], sum1);
  }
  __syncthreads();

  // ---- publish partials: agent-scope relaxed atomic stores (no cache flush) ----
  if (t < HID_)
    __hip_atomic_store(&part[((size_t)b * NT_ + blockIdx.x) * HID_ + t], sAcc[t],
                       __ATOMIC_RELAXED, __HIP_MEMORY_SCOPE_AGENT);

  // ---- last-block-per-batch via acq_rel counter (release seq orders stores) ----
  if (t == 0)
    sLast = (__hip_atomic_fetch_add(&cnt_g[b], 1, __ATOMIC_ACQ_REL,
                                    __HIP_MEMORY_SCOPE_AGENT) == NT_ - 1);
  __syncthreads();
  if (!sLast) return;

  float* sT0 = &sW1s[0][0];             // dead staging space reused for the tail
  float* sT1 = &sW1s[2][0];

  if (t < HID_) {
    float a = 0.f;
    #pragma unroll
    for (int p = 0; p < NT_; ++p)
      a += __hip_atomic_load(&part[((size_t)b * NT_ + p) * HID_ + t],
                             __ATOMIC_RELAXED, __HIP_MEMORY_SCOPE_AGENT);
    sT0[t] = a;
  }
  __syncthreads();
  if (t < HID_) {
    float v = b3[t];
    #pragma unroll 16
    for (int k = 0; k < HID_; ++k) v += sT0[k] * W3[k * HID_ + t];
    sT1[t] = fmaxf(v, 0.f);
  }
  __syncthreads();
  if (t < HID_) {
    float w = b4[t];
    #pragma unroll 16
    for (int k = 0; k < HID_; ++k) w += sT1[k] * W4[k * HID_ + t];
    sT0[t] = fmaxf(w, 0.f);              // sT0 now = h4
  }
  __syncthreads();
  if (t < DIM_) {
    float o = b5[t];
    #pragma unroll
    for (int k = 0; k < DIM_; ++k) o += sEnder[k] * W5[k * DIM_ + t];
    #pragma unroll 16
    for (int k = 0; k < HID_; ++k) o += sT0[k] * W5[(DIM_ + k) * DIM_ + t];
    out[b * DIM_ + t] = o;
  }
}

extern "C" void kernel_launch(void* const* d_in, const int* in_sizes, int n_in,
                              void* d_out, int out_size, void* d_ws, size_t ws_size,
                              hipStream_t stream) {
  const float* x   = (const float*)d_in[0];
  const float* adj = (const float*)d_in[1];
  const float* W1  = (const float*)d_in[2];   // W_n2e [32,128]
  const float* b1  = (const float*)d_in[3];
  const float* W2  = (const float*)d_in[4];   // W_e2e [128,128]
  const float* b2  = (const float*)d_in[5];
  const float* W3  = (const float*)d_in[6];   // W_e2n
  const float* b3  = (const float*)d_in[7];
  const float* W4  = (const float*)d_in[8];   // W_n2n
  const float* b4  = (const float*)d_in[9];
  const float* W5  = (const float*)d_in[10];  // W_out [144,16]
  const float* b5  = (const float*)d_in[11];
  const int*   ip  = (const int*)d_in[12];
  float* out  = (float*)d_out;
  float* part = (float*)d_ws;                 // [B, NT_, HID] fp32 partials
  int*   cntg = (int*)((char*)d_ws + (size_t)B_ * NT_ * HID_ * sizeof(float));

  hipMemsetAsync(cntg, 0, B_ * sizeof(int), stream);   // counters (ws is 0xAA-poisoned)
  edge_kernel<<<dim3(NT_, B_), 256, 0, stream>>>(x, adj, W1, b1, W2, b2,
                                                 W3, b3, W4, b4, W5, b5,
                                                 ip, part, cntg, out);
}

// Round 14
// 122.325 us; speedup vs baseline: 1.3292x; 1.0506x over previous
//
#include <hip/hip_runtime.h>
#include <hip/hip_bf16.h>

#define B_    128
#define N_    4096
#define DIM_  16
#define HID_  128
#define NT_   4             // grid.x tiles -> 512 blocks, 2 resident/CU
#define ROWS_ (N_ / NT_)    // 1024 adj rows per block

typedef __bf16 bf16x8 __attribute__((ext_vector_type(8)));
typedef float floatx16 __attribute__((ext_vector_type(16)));
typedef unsigned int u32;

__device__ inline bf16x8 load_cvt8(const float* __restrict__ p) {
  const float4 u = *(const float4*)p;
  const float4 v = *(const float4*)(p + 4);
  bf16x8 r;
  r[0] = (__bf16)u.x; r[1] = (__bf16)u.y; r[2] = (__bf16)u.z; r[3] = (__bf16)u.w;
  r[4] = (__bf16)v.x; r[5] = (__bf16)v.y; r[6] = (__bf16)v.z; r[7] = (__bf16)v.w;
  return r;
}

// FINAL (= R11, measured best 122.6 us): zero-shuffle repack via feature
// permutation pi = swap(bit2<->bit3) of k applied to W2's rows at staging
// (contraction invariant under simultaneous permutation of h1 features and
// W2 rows) -> stage-A C-layout IS the stage-B A-operand layout, no
// cross-lane ops. Wave tile 32 rows x 64 cols; W2 B-frags register-resident
// (read once from XOR-swizzled LDS); ballot compaction of active rows;
// ender@W1[16:32]+b1 folded into a spare-K bias MFMA; one-ahead x prefetch;
// (256,2) envelope -- the only spill-free occupancy point (R2/R5/R7/R8/R9
// all spilled at higher caps). Fusion variants (R12 threadfence, R13 agent
// atomics) measured slower; two-dispatch graph overlaps the tail fine.
__global__ __launch_bounds__(256, 2) void edge_kernel(
    const float* __restrict__ x, const float* __restrict__ adj,
    const float* __restrict__ W1, const float* __restrict__ b1,
    const float* __restrict__ W2, const float* __restrict__ b2,
    const int* __restrict__ ip, float* __restrict__ part)
{
  // sW2: col c = 128 contiguous bf16 (16 granules of 8), granule slot gg^(c&15),
  // rows bit2<->bit3-permuted: granule gg element j holds
  // W2[16*(gg>>1) + 8*(j>>2) + 4*(gg&1) + (j&3)][c].
  __shared__ __align__(16) __bf16 sW2[HID_ * HID_];
  __shared__ __align__(16) float sW1s[DIM_][HID_];   // W1 starter rows, coalesced staged
  __shared__ int   sIdx[ROWS_ + 192];
  __shared__ float sAcc[HID_];
  __shared__ float sB1[HID_];
  __shared__ float sEnder[DIM_];
  __shared__ int   sCnt;

  const int t  = threadIdx.x;
  const int b  = blockIdx.y;
  const int n0 = blockIdx.x * ROWS_;
  const int ii = __ldg(ip);

  const int wave = t >> 6, lane = t & 63;
  const int half = lane >> 5, l31 = lane & 31;
  const int rg = wave >> 1;           // row-group: chunks rg*32, step 64
  const int ch = wave & 1;            // col-half: cols ch*64 .. ch*64+63

  if (t == 0) sCnt = 0;
  if (t < HID_) sAcc[t] = 0.f;
  if (t < DIM_) sEnder[t] = x[((size_t)b * N_ + ii) * DIM_ + t];
  __syncthreads();

  // ---- ballot-based compaction: 1 LDS atomic per wave-iter ----
  #pragma unroll
  for (int r = t; r < ROWS_; r += 256) {
    const bool act = adj[n0 + r] != 0.f;
    const unsigned long long m = __ballot(act);
    int base = 0;
    if (lane == 0) base = atomicAdd(&sCnt, __popcll(m));
    base = __shfl(base, 0);
    if (act) {
      const int pre = __builtin_amdgcn_mbcnt_hi((u32)(m >> 32),
                      __builtin_amdgcn_mbcnt_lo((u32)m, 0));
      sIdx[base + pre] = n0 + r;
    }
  }

  // ---- W1 starter rows -> LDS, fully coalesced ----
  #pragma unroll
  for (int e = t; e < DIM_ * HID_; e += 256) sW1s[e >> 7][e & 127] = W1[e];

  // ---- stage W2^T into LDS, bf16, XOR-swizzled granules, pi-permuted rows ----
  #pragma unroll
  for (int e = 0; e < 8; ++e) {
    const int G = t * 8 + e;            // granule id: c = G>>4, gg = G&15
    const int c = G >> 4, gg = G & 15;
    bf16x8 v;
    #pragma unroll
    for (int j = 0; j < 8; ++j) {
      const int row = ((gg >> 1) << 4) + ((j >> 2) << 3) + ((gg & 1) << 2) + (j & 3);
      v[j] = (__bf16)W2[row * HID_ + c];
    }
    *(bf16x8*)&sW2[(c << 7) + ((gg ^ (c & 15)) << 3)] = v;
  }

  // ---- cooperative ender-fold: sB1[f] = b1[f] + ender . W1[16:32, f] ----
  if (t < HID_) {
    float s = b1[t];
    #pragma unroll
    for (int k = 0; k < DIM_; ++k) s += sEnder[k] * W1[(DIM_ + k) * HID_ + t];
    sB1[t] = s;
  }

  const float bv0 = b2[ch * 64 + l31], bv1 = b2[ch * 64 + 32 + l31];

  __syncthreads();                       // sIdx/sCnt/sW2/sW1s/sB1 ready
  const int cnt = sCnt;
  const int nch64 = (cnt + 63) >> 6;
  const int end = nch64 * 64;
  for (int p = cnt + t; p < end + 128; p += 256) sIdx[p] = n0;  // pad + prefetch slack

  // W1^T A-frags from LDS (m=feat=l31+32ft, k=half*8+j)
  bf16x8 w1f[4];
  #pragma unroll
  for (int ft = 0; ft < 4; ++ft) {
    bf16x8 v;
    #pragma unroll
    for (int j = 0; j < 8; ++j) v[j] = (__bf16)sW1s[half * 8 + j][ft * 32 + l31];
    w1f[ft] = v;
  }

  // ---- W2 B-frags for this wave's col-half: read ONCE from swizzled LDS ----
  bf16x8 w2r[16];                        // [s] = col-tile0, [8+s] = col-tile1
  {
    const int c0 = ch * 64 + l31;
    const __bf16* base0 = &sW2[(c0 << 7)];
    const __bf16* base1 = &sW2[((c0 + 32) << 7)];
    #pragma unroll
    for (int s = 0; s < 8; ++s) {
      const int gp = ((s << 1) + half) ^ (c0 & 15);
      w2r[s]     = *(const bf16x8*)(base0 + (gp << 3));
      w2r[8 + s] = *(const bf16x8*)(base1 + (gp << 3));
    }
  }

  // bias delivered via spare-K MFMA (k=0: bf16 hi, k=1: bf16 residual)
  bf16x8 a2f[4], onef;
  #pragma unroll
  for (int j = 0; j < 8; ++j) onef[j] = (__bf16)0.f;
  if (half == 0) { onef[0] = (__bf16)1.f; onef[1] = (__bf16)1.f; }
  #pragma unroll
  for (int ft = 0; ft < 4; ++ft) {
    bf16x8 v;
    #pragma unroll
    for (int j = 0; j < 8; ++j) v[j] = (__bf16)0.f;
    if (half == 0) {
      const float s = sB1[ft * 32 + l31];
      const __bf16 hi = (__bf16)s;
      v[0] = hi;
      v[1] = (__bf16)(s - (float)hi);
    }
    a2f[ft] = v;
  }
  __syncthreads();                       // pad visible

  float sum0 = 0.f, sum1 = 0.f;
  floatx16 zf;
  #pragma unroll
  for (int r = 0; r < 16; ++r) zf[r] = 0.f;

  // prefetch first gather (pad guarantees sIdx valid)
  int cb = rg * 32;
  bf16x8 xf;
  {
    const int row = sIdx[cb + l31];
    xf = load_cvt8(&x[((size_t)b * N_ + row) * DIM_ + half * 8]);
  }

  for (; cb < end; cb += 64) {
    const int nrow = sIdx[cb + 64 + l31];            // next iter (pad-safe)

    // ---- stage A: h1^T tiles; pi-permutation makes the repack register-local ----
    bf16x8 af[8];                        // stage-B A-frags, k = s*16 + half*8 + j
    #pragma unroll
    for (int ft = 0; ft < 4; ++ft) {
      floatx16 hc = __builtin_amdgcn_mfma_f32_32x32x16_bf16(w1f[ft], xf, zf, 0, 0, 0);
      hc = __builtin_amdgcn_mfma_f32_32x32x16_bf16(a2f[ft], onef, hc, 0, 0, 0);
      bf16x8 a0, a1;
      #pragma unroll
      for (int j = 0; j < 8; ++j) {
        a0[j] = (__bf16)fmaxf(hc[j],     0.f);
        a1[j] = (__bf16)fmaxf(hc[8 + j], 0.f);
      }
      af[2 * ft]     = a0;
      af[2 * ft + 1] = a1;
    }

    // prefetch next x gather; its waitcnt lands after stage B
    const bf16x8 nxf = load_cvt8(&x[((size_t)b * N_ + nrow) * DIM_ + half * 8]);

    // ---- stage B: 32 rows x 64 cols, K=128; B-frags from REGISTERS ----
    floatx16 c0 = zf, c1 = zf;
    #pragma unroll
    for (int s = 0; s < 8; ++s) {
      c0 = __builtin_amdgcn_mfma_f32_32x32x16_bf16(af[s], w2r[s],     c0, 0, 0, 0);
      c1 = __builtin_amdgcn_mfma_f32_32x32x16_bf16(af[s], w2r[8 + s], c1, 0, 0, 0);
    }

    // ---- epilogue: bias + relu + row-sum (row m=(r&3)+8*(r>>2)+4*half) ----
    if (cb + 32 <= cnt) {
      #pragma unroll
      for (int r = 0; r < 16; ++r) {
        sum0 += fmaxf(c0[r] + bv0, 0.f);
        sum1 += fmaxf(c1[r] + bv1, 0.f);
      }
    } else {
      #pragma unroll
      for (int r = 0; r < 16; ++r) {
        const int q = cb + (r & 3) + ((r >> 2) << 3) + (half << 2);
        if (q < cnt) {
          sum0 += fmaxf(c0[r] + bv0, 0.f);
          sum1 += fmaxf(c1[r] + bv1, 0.f);
        }
      }
    }
    xf = nxf;
  }

  // fold halves; two waves share each col-half -> LDS atomics
  sum0 += __shfl_xor(sum0, 32);
  sum1 += __shfl_xor(sum1, 32);
  if (half == 0) {
    atomicAdd(&sAcc[ch * 64 + l31],      sum0);
    atomicAdd(&sAcc[ch * 64 + 32 + l31], sum1);
  }
  __syncthreads();
  if (t < HID_) part[((size_t)b * NT_ + blockIdx.x) * HID_ + t] = sAcc[t];
}

// acc = sum partials; h3 = relu(acc@W3+b3); h4 = relu(h3@W4+b4);
// out = [x[:,i,:] | h4] @ W5 + b5   (all fp32, exact)
__global__ void tail_kernel(
    const float* __restrict__ x, const float* __restrict__ part,
    const float* __restrict__ W3, const float* __restrict__ b3,
    const float* __restrict__ W4, const float* __restrict__ b4,
    const float* __restrict__ W5, const float* __restrict__ b5,
    const int* __restrict__ ip, float* __restrict__ out)
{
  const int b = blockIdx.x, t = threadIdx.x;   // 128 threads
  __shared__ float s0[HID_], s1[HID_], s2[HID_], se[DIM_];
  const int ii = __ldg(ip);
  if (t < DIM_) se[t] = x[((size_t)b * N_ + ii) * DIM_ + t];
  float a = 0.f;
  #pragma unroll
  for (int p = 0; p < NT_; ++p) a += part[((size_t)b * NT_ + p) * HID_ + t];
  s0[t] = a;
  __syncthreads();
  float v = b3[t];
  #pragma unroll 16
  for (int k = 0; k < HID_; ++k) v += s0[k] * W3[k * HID_ + t];
  s1[t] = fmaxf(v, 0.f);
  __syncthreads();
  float w = b4[t];
  #pragma unroll 16
  for (int k = 0; k < HID_; ++k) w += s1[k] * W4[k * HID_ + t];
  s2[t] = fmaxf(w, 0.f);
  __syncthreads();
  if (t < DIM_) {
    float o = b5[t];
    #pragma unroll
    for (int k = 0; k < DIM_; ++k) o += se[k] * W5[k * DIM_ + t];
    #pragma unroll 16
    for (int k = 0; k < HID_; ++k) o += s2[k] * W5[(DIM_ + k) * DIM_ + t];
    out[b * DIM_ + t] = o;
  }
}

extern "C" void kernel_launch(void* const* d_in, const int* in_sizes, int n_in,
                              void* d_out, int out_size, void* d_ws, size_t ws_size,
                              hipStream_t stream) {
  const float* x   = (const float*)d_in[0];
  const float* adj = (const float*)d_in[1];
  const float* W1  = (const float*)d_in[2];   // W_n2e [32,128]
  const float* b1  = (const float*)d_in[3];
  const float* W2  = (const float*)d_in[4];   // W_e2e [128,128]
  const float* b2  = (const float*)d_in[5];
  const float* W3  = (const float*)d_in[6];   // W_e2n
  const float* b3  = (const float*)d_in[7];
  const float* W4  = (const float*)d_in[8];   // W_n2n
  const float* b4  = (const float*)d_in[9];
  const float* W5  = (const float*)d_in[10];  // W_out [144,16]
  const float* b5  = (const float*)d_in[11];
  const int*   ip  = (const int*)d_in[12];
  float* out  = (float*)d_out;
  float* part = (float*)d_ws;                 // [B, NT_, HID] fp32 partials

  edge_kernel<<<dim3(NT_, B_), 256, 0, stream>>>(x, adj, W1, b1, W2, b2, ip, part);
  tail_kernel<<<B_, HID_, 0, stream>>>(x, part, W3, b3, W4, b4, W5, b5, ip, out);
}